// Round 1
// baseline (4994.286 us; speedup 1.0000x reference)
//
#include <hip/hip_runtime.h>
#include <math.h>

#define B_ 4
#define L_ 2048
#define E_ 1024
#define H_ 16
#define D_ 64
#define FF_ 2816
#define M_ (B_*L_)     // 8192 rows
#define E4_ 4096
#define CH_ 64
#define NC_ (L_/CH_)   // 32 chunks

// ---------------------------------------------------------------------------
// reductions
// ---------------------------------------------------------------------------
__device__ inline void wave_reduce2(float& a, float& b) {
#pragma unroll
  for (int off = 1; off < 64; off <<= 1) {
    a += __shfl_xor(a, off);
    b += __shfl_xor(b, off);
  }
}

// ---------------------------------------------------------------------------
// row LayerNorm over E_=1024: one block (256 thr) per row.
// out = (x-mean)*rsqrt(var+1e-5)*g + b   (+ res_after if non-null)
// ---------------------------------------------------------------------------
__global__ __launch_bounds__(256) void ln_rows(
    const float* __restrict__ in, const float* __restrict__ g,
    const float* __restrict__ bb, const float* __restrict__ res_after,
    float* __restrict__ out)
{
  int row = blockIdx.x;
  int t = threadIdx.x;
  float4 v = ((const float4*)(in + (size_t)row * E_))[t];
  float s  = v.x + v.y + v.z + v.w;
  float s2 = v.x*v.x + v.y*v.y + v.z*v.z + v.w*v.w;
  wave_reduce2(s, s2);
  __shared__ float ra[4], rb[4];
  int w = t >> 6;
  if ((t & 63) == 0) { ra[w] = s; rb[w] = s2; }
  __syncthreads();
  s  = ra[0] + ra[1] + ra[2] + ra[3];
  s2 = rb[0] + rb[1] + rb[2] + rb[3];
  float mean = s * (1.f / E_);
  float var  = s2 * (1.f / E_) - mean * mean;
  float r = rsqrtf(var + 1e-5f);
  float4 gv = ((const float4*)g)[t];
  float4 bv = ((const float4*)bb)[t];
  float4 o;
  o.x = (v.x - mean) * r * gv.x + bv.x;
  o.y = (v.y - mean) * r * gv.y + bv.y;
  o.z = (v.z - mean) * r * gv.z + bv.z;
  o.w = (v.w - mean) * r * gv.w + bv.w;
  if (res_after) {
    float4 rv = ((const float4*)(res_after + (size_t)row * E_))[t];
    o.x += rv.x; o.y += rv.y; o.z += rv.z; o.w += rv.w;
  }
  ((float4*)(out + (size_t)row * E_))[t] = o;
}

// ---------------------------------------------------------------------------
// k <- k / max(||k||_2, 1e-5) in place, one block per row
// ---------------------------------------------------------------------------
__global__ __launch_bounds__(256) void knorm_rows(float* __restrict__ k)
{
  int row = blockIdx.x;
  int t = threadIdx.x;
  float4* kp = (float4*)(k + (size_t)row * E_);
  float4 v = kp[t];
  float s2 = v.x*v.x + v.y*v.y + v.z*v.z + v.w*v.w;
  float d0 = 0.f;
  wave_reduce2(s2, d0);
  __shared__ float rb2[4];
  int w = t >> 6;
  if ((t & 63) == 0) rb2[w] = s2;
  __syncthreads();
  s2 = rb2[0] + rb2[1] + rb2[2] + rb2[3];
  float sc = 1.f / fmaxf(sqrtf(s2), 1e-5f);
  v.x *= sc; v.y *= sc; v.z *= sc; v.w *= sc;
  kp[t] = v;
}

// ---------------------------------------------------------------------------
// cumsum helpers: chunk partial sums over L (chunk=CH_), exclusive scan,
// then per-chunk serial passes.
// ---------------------------------------------------------------------------
__global__ __launch_bounds__(256) void chunk_partials(
    const float* __restrict__ x, float* __restrict__ S)
{
  int c = blockIdx.x, b = blockIdx.y, t = threadIdx.x;
  const float4* xp = (const float4*)(x + ((size_t)b * L_ + (size_t)c * CH_) * E_);
  float4 acc = make_float4(0.f, 0.f, 0.f, 0.f);
  for (int l = 0; l < CH_; ++l) {
    float4 v = xp[(size_t)l * (E_/4) + t];
    acc.x += v.x; acc.y += v.y; acc.z += v.z; acc.w += v.w;
  }
  ((float4*)(S + ((size_t)b * NC_ + c) * E_))[t] = acc;
}

// exclusive scan of chunk partials in place: S[b,c,e] <- sum_{c'<c} S[b,c',e]
__global__ __launch_bounds__(256) void scan_partials(float* __restrict__ S)
{
  int b = blockIdx.x, t = threadIdx.x;
  float4 run = make_float4(0.f, 0.f, 0.f, 0.f);
  for (int c = 0; c < NC_; ++c) {
    float4* p = (float4*)(S + ((size_t)b * NC_ + c) * E_);
    float4 v = p[t];
    p[t] = run;
    run.x += v.x; run.y += v.y; run.z += v.z; run.w += v.w;
  }
}

// ---------------------------------------------------------------------------
// align + gate: one wave per (chunk, head, batch).  Thread d owns column
// e = h*64+d.  xc = exclusive chunk offset + running in-chunk sum (inclusive).
// align = sum_d LN(x_h)*LN(xc_h) / 8 ; gated = x_h * sigmoid(align).
// Also emits chunk partial sums of gated into G.
// ---------------------------------------------------------------------------
__global__ __launch_bounds__(64) void align_gate(
    const float* __restrict__ xmlp, const float* __restrict__ Sx,
    const float* __restrict__ gh, const float* __restrict__ bh,
    float* __restrict__ gated, float* __restrict__ G)
{
  int c = blockIdx.x, h = blockIdx.y, b = blockIdx.z;
  int d = threadIdx.x;
  int e = h * D_ + d;
  float xc = Sx[((size_t)b * NC_ + c) * E_ + e];   // exclusive prefix
  float gsum = 0.f;
  float ghd = gh[d], bhd = bh[d];
  const float* xp = xmlp + ((size_t)b * L_ + (size_t)c * CH_) * E_ + e;
  float* gp = gated + ((size_t)b * L_ + (size_t)c * CH_) * E_ + e;
  for (int l = 0; l < CH_; ++l) {
    float xv = xp[(size_t)l * E_];
    xc += xv;                                      // inclusive cumsum
    float sx = xv, sx2 = xv * xv, sc = xc, sc2 = xc * xc;
#pragma unroll
    for (int off = 1; off < 64; off <<= 1) {
      sx  += __shfl_xor(sx, off);
      sx2 += __shfl_xor(sx2, off);
      sc  += __shfl_xor(sc, off);
      sc2 += __shfl_xor(sc2, off);
    }
    float mx = sx * (1.f/64.f), vx = sx2 * (1.f/64.f) - mx * mx;
    float mc = sc * (1.f/64.f), vc = sc2 * (1.f/64.f) - mc * mc;
    float nx = (xv - mx) * rsqrtf(vx + 1e-5f) * ghd + bhd;
    float ncv = (xc - mc) * rsqrtf(vc + 1e-5f) * ghd + bhd;
    float dotv = nx * ncv;
#pragma unroll
    for (int off = 1; off < 64; off <<= 1) dotv += __shfl_xor(dotv, off);
    float align = dotv * 0.125f;                   // / sqrt(64)
    float sig = 1.f / (1.f + expf(-align));
    float gv = xv * sig;
    gp[(size_t)l * E_] = gv;
    gsum += gv;
  }
  G[((size_t)b * NC_ + c) * E_ + e] = gsum;
}

// ---------------------------------------------------------------------------
// context cumsum + residual: t_out = x_mlp + cumsum(gated)
// ---------------------------------------------------------------------------
__global__ __launch_bounds__(256) void context_add(
    const float* __restrict__ gated, const float* __restrict__ Gx,
    const float* __restrict__ xmlp, float* __restrict__ t_out)
{
  int c = blockIdx.x, b = blockIdx.y, t = threadIdx.x;
  float4 run = ((const float4*)(Gx + ((size_t)b * NC_ + c) * E_))[t];
  size_t base = ((size_t)b * L_ + (size_t)c * CH_) * (E_/4);
  const float4* gp = (const float4*)gated;
  const float4* xp = (const float4*)xmlp;
  float4* op = (float4*)t_out;
  for (int l = 0; l < CH_; ++l) {
    size_t idx = base + (size_t)l * (E_/4) + t;
    float4 g = gp[idx];
    run.x += g.x; run.y += g.y; run.z += g.z; run.w += g.w;
    float4 x = xp[idx];
    float4 o;
    o.x = x.x + run.x; o.y = x.y + run.y; o.z = x.z + run.z; o.w = x.w + run.w;
    op[idx] = o;
  }
}

// ---------------------------------------------------------------------------
// Generic f32 tiled GEMM, 128x128 tile, BK=32, 256 threads, 8x8 per thread.
// BT=false: B is KxN row-major (weights).  BT=true: B is NxK row-major (k^T).
// ---------------------------------------------------------------------------
enum { EPI_PLAIN = 0, EPI_BIAS = 1, EPI_SILU = 2, EPI_SIG = 3,
       EPI_BIAS_RES = 4, EPI_VDYN = 5, EPI_PV = 6, EPI_TRIL = 7 };

struct GemmP {
  const float* A; const float* Bm; float* C;
  int N, K;
  long long sA, sB, sC;
  const float* bias;
  const float* res;  long long sRes;
  const float* aux;  long long sAux;
  int epi; int causal;   // causal: 0 none, 1 tril mask+skip, 2 kend=row0+BM
};

#define BM 128
#define BN 128
#define BKK 32

template <bool BT>
__global__ __launch_bounds__(256) void gemm_f32(GemmP p)
{
  __shared__ float As[BKK][BM];
  __shared__ float Bs[BKK][BN];
  int bz = blockIdx.z;
  const float* A = p.A + (size_t)bz * p.sA;
  const float* Bmat = p.Bm + (size_t)bz * p.sB;
  float* C = p.C + (size_t)bz * p.sC;
  int row0 = blockIdx.y * BM;
  int col0 = blockIdx.x * BN;
  int tid = threadIdx.x;
  int tr = tid >> 4, tc = tid & 15;

  if (p.causal == 1 && col0 >= row0 + BM) {       // fully above diagonal
    float4 z = make_float4(0.f, 0.f, 0.f, 0.f);
#pragma unroll
    for (int i = 0; i < 8; ++i) {
      int r = row0 + tr * 8 + i;
      float* cp = C + (size_t)r * p.N + col0 + tc * 8;
      ((float4*)cp)[0] = z; ((float4*)cp)[1] = z;
    }
    return;
  }

  int kend = p.K;
  if (p.causal == 2) kend = min(p.K, row0 + BM);

  float acc[8][8] = {};

  for (int k0 = 0; k0 < kend; k0 += BKK) {
    // A tile: BM x BKK, stored transposed As[k][m]
#pragma unroll
    for (int i = 0; i < 4; ++i) {
      int f = tid + 256 * i;            // 0..1023
      int r = f >> 3, c4 = f & 7;
      float4 v = *(const float4*)(A + (size_t)(row0 + r) * p.K + k0 + c4 * 4);
      As[c4*4+0][r] = v.x; As[c4*4+1][r] = v.y;
      As[c4*4+2][r] = v.z; As[c4*4+3][r] = v.w;
    }
    if (!BT) {
      // B tile: BKK x BN straight
#pragma unroll
      for (int i = 0; i < 4; ++i) {
        int f = tid + 256 * i;
        int r = f >> 5, c4 = f & 31;
        float4 v = *(const float4*)(Bmat + (size_t)(k0 + r) * p.N + col0 + c4 * 4);
        *(float4*)&Bs[r][c4 * 4] = v;
      }
    } else {
      // B stored N x K: tile BN x BKK, store transposed Bs[k][n]
#pragma unroll
      for (int i = 0; i < 4; ++i) {
        int f = tid + 256 * i;
        int r = f >> 3, c4 = f & 7;
        float4 v = *(const float4*)(Bmat + (size_t)(col0 + r) * p.K + k0 + c4 * 4);
        Bs[c4*4+0][r] = v.x; Bs[c4*4+1][r] = v.y;
        Bs[c4*4+2][r] = v.z; Bs[c4*4+3][r] = v.w;
      }
    }
    __syncthreads();
#pragma unroll
    for (int k = 0; k < BKK; ++k) {
      float a[8], b[8];
      *(float4*)&a[0] = *(float4*)&As[k][tr * 8];
      *(float4*)&a[4] = *(float4*)&As[k][tr * 8 + 4];
      *(float4*)&b[0] = *(float4*)&Bs[k][tc * 8];
      *(float4*)&b[4] = *(float4*)&Bs[k][tc * 8 + 4];
#pragma unroll
      for (int i = 0; i < 8; ++i)
#pragma unroll
        for (int j = 0; j < 8; ++j) acc[i][j] += a[i] * b[j];
    }
    __syncthreads();
  }

  const float INV32 = 0.03125f;
  for (int i = 0; i < 8; ++i) {
    int r = row0 + tr * 8 + i;
    size_t rowoff = (size_t)r * p.N;
    for (int j = 0; j < 8; ++j) {
      int ccol = col0 + tc * 8 + j;
      size_t idx = rowoff + ccol;
      float v = acc[i][j];
      switch (p.epi) {
        case EPI_PLAIN: break;
        case EPI_BIAS: v += p.bias[ccol]; break;
        case EPI_SILU: v += p.bias[ccol]; v = v / (1.f + expf(-v)); break;
        case EPI_SIG:  v += p.bias[ccol]; v = 1.f / (1.f + expf(-v)); break;
        case EPI_BIAS_RES:
          v += p.bias[ccol] + p.res[(size_t)bz * p.sRes + idx]; break;
        case EPI_VDYN:
          v = p.aux[(size_t)bz * p.sAux + idx] *
              (p.res[(size_t)bz * p.sRes + idx] - v * INV32); break;
        case EPI_PV:
          v = (p.res[(size_t)bz * p.sRes + idx] + v * INV32) * INV32; break;
        case EPI_TRIL: v = (ccol <= r) ? v : 0.f; break;
      }
      C[idx] = v;
    }
  }
}

// ---------------------------------------------------------------------------
// host orchestration
// ---------------------------------------------------------------------------
static void launch_gemm(const float* A, const float* Bmat, float* C,
                        int M, int N, int K,
                        long long sA, long long sB, long long sC, int nb,
                        const float* bias, const float* res, long long sRes,
                        const float* aux, long long sAux,
                        int epi, int causal, bool BT, hipStream_t stream)
{
  GemmP p;
  p.A = A; p.Bm = Bmat; p.C = C; p.N = N; p.K = K;
  p.sA = sA; p.sB = sB; p.sC = sC;
  p.bias = bias; p.res = res; p.sRes = sRes; p.aux = aux; p.sAux = sAux;
  p.epi = epi; p.causal = causal;
  dim3 grid(N / BN, M / BM, nb), blk(256);
  if (BT) gemm_f32<true><<<grid, blk, 0, stream>>>(p);
  else    gemm_f32<false><<<grid, blk, 0, stream>>>(p);
}

extern "C" void kernel_launch(void* const* d_in, const int* in_sizes, int n_in,
                              void* d_out, int out_size, void* d_ws, size_t ws_size,
                              hipStream_t stream)
{
  const float* x      = (const float*)d_in[0];
  const float* g_norm = (const float*)d_in[1];
  const float* b_norm = (const float*)d_in[2];
  const float* W1     = (const float*)d_in[3];
  const float* b1     = (const float*)d_in[4];
  const float* W2     = (const float*)d_in[5];
  const float* b2     = (const float*)d_in[6];
  const float* g_head = (const float*)d_in[7];
  const float* b_head = (const float*)d_in[8];
  const float* memW   = (const float*)d_in[9];
  const float* g_mem  = (const float*)d_in[10];
  const float* b_mem  = (const float*)d_in[11];
  const float* W_q    = (const float*)d_in[12];
  const float* b_q    = (const float*)d_in[13];
  const float* W_k    = (const float*)d_in[14];
  const float* b_k    = (const float*)d_in[15];
  const float* W_v    = (const float*)d_in[16];
  const float* b_v    = (const float*)d_in[17];
  const float* W_g    = (const float*)d_in[18];
  const float* b_g    = (const float*)d_in[19];
  // d_in[20], d_in[21] = W_mg, b_mg: unused by the reference forward
  const float* W_o    = (const float*)d_in[22];
  const float* b_o    = (const float*)d_in[23];
  const float* W_op   = (const float*)d_in[24];
  const float* b_op   = (const float*)d_in[25];
  const float* g_ctx  = (const float*)d_in[26];
  const float* b_ctx  = (const float*)d_in[27];
  // d_in[28] = seq_dim (always 1)

  float* out = (float*)d_out;
  float* ws  = (float*)d_ws;

  // workspace layout (floats)
  const size_t BIGSZ = (size_t)M_ * E4_;      // 33,554,432 (h1 then out_h)
  const size_t PSZ   = (size_t)M_ * E_;       //  8,388,608
  const size_t SSZ   = (size_t)B_ * NC_ * E_; //    131,072
  size_t off = 0;
  float* big  = ws + off; off += BIGSZ;
  float* xmlp = ws + off; off += PSZ;
  float* p1   = ws + off; off += PSZ;   // x_norm -> gated -> q
  float* p3   = ws + off; off += PSZ;   // t -> k -> out
  float* p4   = ws + off; off += PSZ;   // ctx -> mem_out
  float* p5   = ws + off; off += PSZ;   // v -> v_dyn
  float* p6   = ws + off; off += PSZ;   // gate
  float* Sb   = ws + off; off += SSZ;   // x_mlp chunk partials
  float* Gb   = ws + off; off += SSZ;   // gated chunk partials
  if (ws_size < off * sizeof(float)) return;   // insufficient workspace

  float* y_out  = out;
  float* sc_out = out + (size_t)M_ * E_;       // scores_causal (B,L,L)

  // 1. x_norm = LN(x)
  ln_rows<<<M_, 256, 0, stream>>>(x, g_norm, b_norm, nullptr, p1);
  // 2. h1 = silu(x_norm @ W1 + b1)
  launch_gemm(p1, W1, big, M_, FF_, E_, 0,0,0, 1, b1, nullptr,0, nullptr,0,
              EPI_SILU, 0, false, stream);
  // 3. x_mlp = x + h1 @ W2 + b2
  launch_gemm(big, W2, xmlp, M_, E_, FF_, 0,0,0, 1, b2, x,0, nullptr,0,
              EPI_BIAS_RES, 0, false, stream);
  // 4-5. xc chunk partials + exclusive scan
  chunk_partials<<<dim3(NC_, B_), 256, 0, stream>>>(xmlp, Sb);
  scan_partials<<<B_, 256, 0, stream>>>(Sb);
  // 6. align + gated (+ gated chunk partials)
  align_gate<<<dim3(NC_, H_, B_), 64, 0, stream>>>(xmlp, Sb, g_head, b_head, p1, Gb);
  // 7. scan gated partials
  scan_partials<<<B_, 256, 0, stream>>>(Gb);
  // 8. t = x_mlp + context
  context_add<<<dim3(NC_, B_), 256, 0, stream>>>(p1, Gb, xmlp, p3);
  // 9. ctx = LN(t)
  ln_rows<<<M_, 256, 0, stream>>>(p3, g_mem, b_mem, nullptr, p4);
  // 10-14. projections
  launch_gemm(p4, W_q, p1, M_, E_, E_, 0,0,0,1, b_q, nullptr,0, nullptr,0,
              EPI_BIAS, 0, false, stream);
  launch_gemm(p4, W_k, p3, M_, E_, E_, 0,0,0,1, b_k, nullptr,0, nullptr,0,
              EPI_BIAS, 0, false, stream);
  knorm_rows<<<M_, 256, 0, stream>>>(p3);
  launch_gemm(p4, W_v, p5, M_, E_, E_, 0,0,0,1, b_v, nullptr,0, nullptr,0,
              EPI_BIAS, 0, false, stream);
  launch_gemm(p4, W_g, p6, M_, E_, E_, 0,0,0,1, b_g, nullptr,0, nullptr,0,
              EPI_SIG, 0, false, stream);
  // 15. v_dyn = gate * (v - (k @ mem)/32)   (in place into p5)
  launch_gemm(p3, memW, p5, M_, E_, E_, 0,0,0,1, nullptr, p5,0, p6,0,
              EPI_VDYN, 0, false, stream);
  // 16. scores = tril(q @ k^T)  -> d_out
  launch_gemm(p1, p3, sc_out, L_, L_, E_,
              (long long)L_*E_, (long long)L_*E_, (long long)L_*L_, B_,
              nullptr, nullptr,0, nullptr,0, EPI_TRIL, 1, true, stream);
  // 17. mem_out_prev = q @ mem -> p4 (ctx dead)
  launch_gemm(p1, memW, p4, M_, E_, E_, 0,0,0,1, nullptr, nullptr,0, nullptr,0,
              EPI_PLAIN, 0, false, stream);
  // 18. mem_out = (mem_out_prev + scores @ v_dyn / 32) / 32  (in place p4)
  launch_gemm(sc_out, p5, p4, L_, E_, L_,
              (long long)L_*L_, (long long)L_*E_, (long long)L_*E_, B_,
              nullptr, p4, (long long)L_*E_, nullptr,0, EPI_PV, 2, false, stream);
  // 19. out_h = silu(mem_out @ W_o + b_o)
  launch_gemm(p4, W_o, big, M_, E4_, E_, 0,0,0,1, b_o, nullptr,0, nullptr,0,
              EPI_SILU, 0, false, stream);
  // 20. out = out_h @ W_op + b_op  -> p3 (k dead)
  launch_gemm(big, W_op, p3, M_, E_, E4_, 0,0,0,1, b_op, nullptr,0, nullptr,0,
              EPI_BIAS, 0, false, stream);
  // 21. y = x_mlp + LN(out)
  ln_rows<<<M_, 256, 0, stream>>>(p3, g_ctx, b_ctx, xmlp, y_out);
}

// Round 5
// 1603.248 us; speedup vs baseline: 3.1151x; 3.1151x over previous
//
#include <hip/hip_runtime.h>
#include <math.h>

#define B_ 4
#define L_ 2048
#define E_ 1024
#define H_ 16
#define D_ 64
#define FF_ 2816
#define M_ (B_*L_)     // 8192 rows
#define E4_ 4096
#define CH_ 64
#define NC_ (L_/CH_)   // 32 chunks

typedef unsigned short ushort_t;
typedef __attribute__((ext_vector_type(8))) short short8;
typedef __attribute__((ext_vector_type(4))) float f32x4;
typedef __attribute__((ext_vector_type(4))) unsigned short ushort4v;

__device__ inline ushort_t f2b(float x) {
  union { float f; unsigned u; } v; v.f = x;
  unsigned r = v.u + 0x7FFFu + ((v.u >> 16) & 1u);
  return (ushort_t)(r >> 16);
}
__device__ inline float b2f(ushort_t h) {
  union { unsigned u; float f; } v; v.u = ((unsigned)h) << 16; return v.f;
}
// split f32 -> hi (truncated top16) + lo (RNE of residual)
__device__ inline void split8(const float* s, short8& hi, short8& lo) {
#pragma unroll
  for (int i = 0; i < 8; ++i) {
    unsigned u; { union { float f; unsigned x; } c; c.f = s[i]; u = c.x; }
    unsigned hu = u & 0xFFFF0000u;
    hi[i] = (short)(hu >> 16);
    union { unsigned x; float f; } hc; hc.x = hu;
    lo[i] = (short)f2b(s[i] - hc.f);
  }
}

// ---------------------------------------------------------------------------
// reductions
// ---------------------------------------------------------------------------
__device__ inline float wave_sum(float a) {
#pragma unroll
  for (int off = 1; off < 64; off <<= 1) a += __shfl_xor(a, off);
  return a;
}
__device__ inline void wave_reduce2(float& a, float& b) {
#pragma unroll
  for (int off = 1; off < 64; off <<= 1) {
    a += __shfl_xor(a, off);
    b += __shfl_xor(b, off);
  }
}

// ---------------------------------------------------------------------------
// row LayerNorm over E_=1024 (two-pass variance), one block per row.
// ---------------------------------------------------------------------------
__global__ __launch_bounds__(256) void ln_rows(
    const float* __restrict__ in, const float* __restrict__ g,
    const float* __restrict__ bb, const float* __restrict__ res_after,
    float* __restrict__ outf, ushort_t* __restrict__ outb,
    ushort_t* __restrict__ outbl)
{
  int row = blockIdx.x;
  int t = threadIdx.x;
  float4 v = ((const float4*)(in + (size_t)row * E_))[t];
  float s = wave_sum(v.x + v.y + v.z + v.w);
  __shared__ float ra[4], rb[4];
  int w = t >> 6;
  if ((t & 63) == 0) ra[w] = s;
  __syncthreads();
  float mean = (ra[0] + ra[1] + ra[2] + ra[3]) * (1.f / E_);
  float dx = v.x - mean, dy = v.y - mean, dz = v.z - mean, dw = v.w - mean;
  float s2 = wave_sum(dx*dx + dy*dy + dz*dz + dw*dw);
  if ((t & 63) == 0) rb[w] = s2;
  __syncthreads();
  float var = (rb[0] + rb[1] + rb[2] + rb[3]) * (1.f / E_);
  float r = rsqrtf(var + 1e-5f);
  float4 gv = ((const float4*)g)[t];
  float4 bv = ((const float4*)bb)[t];
  float4 o;
  o.x = dx * r * gv.x + bv.x;
  o.y = dy * r * gv.y + bv.y;
  o.z = dz * r * gv.z + bv.z;
  o.w = dw * r * gv.w + bv.w;
  if (res_after) {
    float4 rv = ((const float4*)(res_after + (size_t)row * E_))[t];
    o.x += rv.x; o.y += rv.y; o.z += rv.z; o.w += rv.w;
  }
  if (outf) ((float4*)(outf + (size_t)row * E_))[t] = o;
  if (outb) {
    ushort4v hb; hb.x = f2b(o.x); hb.y = f2b(o.y); hb.z = f2b(o.z); hb.w = f2b(o.w);
    *(ushort4v*)(outb + (size_t)row * E_ + t * 4) = hb;
    if (outbl) {
      ushort4v lb;
      lb.x = f2b(o.x - b2f(hb.x)); lb.y = f2b(o.y - b2f(hb.y));
      lb.z = f2b(o.z - b2f(hb.z)); lb.w = f2b(o.w - b2f(hb.w));
      *(ushort4v*)(outbl + (size_t)row * E_ + t * 4) = lb;
    }
  }
}

// ---------------------------------------------------------------------------
// k <- k / max(||k||_2, 1e-5): f32 in, bf16 hi+lo out
// ---------------------------------------------------------------------------
__global__ __launch_bounds__(256) void knorm_rows(
    const float* __restrict__ kin, ushort_t* __restrict__ kh,
    ushort_t* __restrict__ kl)
{
  int row = blockIdx.x;
  int t = threadIdx.x;
  float4 v = ((const float4*)(kin + (size_t)row * E_))[t];
  float s2 = wave_sum(v.x*v.x + v.y*v.y + v.z*v.z + v.w*v.w);
  __shared__ float rb2[4];
  int w = t >> 6;
  if ((t & 63) == 0) rb2[w] = s2;
  __syncthreads();
  s2 = rb2[0] + rb2[1] + rb2[2] + rb2[3];
  float sc = 1.f / fmaxf(sqrtf(s2), 1e-5f);
  float f0 = v.x * sc, f1 = v.y * sc, f2 = v.z * sc, f3 = v.w * sc;
  ushort4v hb; hb.x = f2b(f0); hb.y = f2b(f1); hb.z = f2b(f2); hb.w = f2b(f3);
  ushort4v lb;
  lb.x = f2b(f0 - b2f(hb.x)); lb.y = f2b(f1 - b2f(hb.y));
  lb.z = f2b(f2 - b2f(hb.z)); lb.w = f2b(f3 - b2f(hb.w));
  *(ushort4v*)(kh + (size_t)row * E_ + t * 4) = hb;
  *(ushort4v*)(kl + (size_t)row * E_ + t * 4) = lb;
}

// ---------------------------------------------------------------------------
// cumsum helpers
// ---------------------------------------------------------------------------
__global__ __launch_bounds__(256) void chunk_partials(
    const float* __restrict__ x, float* __restrict__ S)
{
  int c = blockIdx.x, b = blockIdx.y, t = threadIdx.x;
  const float4* xp = (const float4*)(x + ((size_t)b * L_ + (size_t)c * CH_) * E_);
  float4 acc = make_float4(0.f, 0.f, 0.f, 0.f);
  for (int l = 0; l < CH_; ++l) {
    float4 v = xp[(size_t)l * (E_/4) + t];
    acc.x += v.x; acc.y += v.y; acc.z += v.z; acc.w += v.w;
  }
  ((float4*)(S + ((size_t)b * NC_ + c) * E_))[t] = acc;
}

__global__ __launch_bounds__(256) void scan_partials(float* __restrict__ S)
{
  int b = blockIdx.x, t = threadIdx.x;
  float4 run = make_float4(0.f, 0.f, 0.f, 0.f);
  for (int c = 0; c < NC_; ++c) {
    float4* p = (float4*)(S + ((size_t)b * NC_ + c) * E_);
    float4 v = p[t];
    p[t] = run;
    run.x += v.x; run.y += v.y; run.z += v.z; run.w += v.w;
  }
}

// ---------------------------------------------------------------------------
// align + gate (one wave per chunk,head,batch), two-pass LN
// ---------------------------------------------------------------------------
__global__ __launch_bounds__(64) void align_gate(
    const float* __restrict__ xmlp, const float* __restrict__ Sx,
    const float* __restrict__ gh, const float* __restrict__ bh,
    float* __restrict__ gated, float* __restrict__ G)
{
  int c = blockIdx.x, h = blockIdx.y, b = blockIdx.z;
  int d = threadIdx.x;
  int e = h * D_ + d;
  float xc = Sx[((size_t)b * NC_ + c) * E_ + e];
  float gsum = 0.f;
  float ghd = gh[d], bhd = bh[d];
  const float* xp = xmlp + ((size_t)b * L_ + (size_t)c * CH_) * E_ + e;
  float* gp = gated + ((size_t)b * L_ + (size_t)c * CH_) * E_ + e;
  for (int l = 0; l < CH_; ++l) {
    float xv = xp[(size_t)l * E_];
    xc += xv;
    float sx = xv, sc = xc;
    wave_reduce2(sx, sc);
    float mx = sx * (1.f/64.f), mc = sc * (1.f/64.f);
    float dx = xv - mx, dc = xc - mc;
    float vx = dx * dx, vc = dc * dc;
    wave_reduce2(vx, vc);
    vx *= (1.f/64.f); vc *= (1.f/64.f);
    float nx  = dx * rsqrtf(vx + 1e-5f) * ghd + bhd;
    float ncv = dc * rsqrtf(vc + 1e-5f) * ghd + bhd;
    float dotv = wave_sum(nx * ncv);
    float align = dotv * 0.125f;
    float sig = 1.f / (1.f + expf(-align));
    float gv = xv * sig;
    gp[(size_t)l * E_] = gv;
    gsum += gv;
  }
  G[((size_t)b * NC_ + c) * E_ + e] = gsum;
}

// ---------------------------------------------------------------------------
// t = x_mlp + cumsum(gated)
// ---------------------------------------------------------------------------
__global__ __launch_bounds__(256) void context_add(
    const float* __restrict__ gated, const float* __restrict__ Gx,
    const float* __restrict__ xmlp, float* __restrict__ t_out)
{
  int c = blockIdx.x, b = blockIdx.y, t = threadIdx.x;
  float4 run = ((const float4*)(Gx + ((size_t)b * NC_ + c) * E_))[t];
  size_t base = ((size_t)b * L_ + (size_t)c * CH_) * (E_/4);
  const float4* gp = (const float4*)gated;
  const float4* xp = (const float4*)xmlp;
  float4* op = (float4*)t_out;
  for (int l = 0; l < CH_; ++l) {
    size_t idx = base + (size_t)l * (E_/4) + t;
    float4 g = gp[idx];
    run.x += g.x; run.y += g.y; run.z += g.z; run.w += g.w;
    float4 x = xp[idx];
    float4 o;
    o.x = x.x + run.x; o.y = x.y + run.y; o.z = x.z + run.z; o.w = x.w + run.w;
    op[idx] = o;
  }
}

// ---------------------------------------------------------------------------
// transpose + convert: f32 (R x C) -> bf16 (C x R), hi + optional lo plane
// ---------------------------------------------------------------------------
__global__ __launch_bounds__(256) void wcvt_t(
    const float* __restrict__ in, ushort_t* __restrict__ outh,
    ushort_t* __restrict__ outl, int R, int C)
{
  __shared__ float t[32][33];
  int c0 = blockIdx.x * 32, r0 = blockIdx.y * 32;
  int tid = threadIdx.x;
  int r = tid >> 3, c4 = (tid & 7) * 4;
  float4 v = *(const float4*)(in + (size_t)(r0 + r) * C + c0 + c4);
  t[r][c4] = v.x; t[r][c4+1] = v.y; t[r][c4+2] = v.z; t[r][c4+3] = v.w;
  __syncthreads();
  int c = tid >> 3, r4 = (tid & 7) * 4;
  float f0 = t[r4][c], f1 = t[r4+1][c], f2 = t[r4+2][c], f3 = t[r4+3][c];
  ushort4v hb; hb.x = f2b(f0); hb.y = f2b(f1); hb.z = f2b(f2); hb.w = f2b(f3);
  *(ushort4v*)(outh + (size_t)(c0 + c) * R + r0 + r4) = hb;
  if (outl) {
    ushort4v lb;
    lb.x = f2b(f0 - b2f(hb.x)); lb.y = f2b(f1 - b2f(hb.y));
    lb.z = f2b(f2 - b2f(hb.z)); lb.w = f2b(f3 - b2f(hb.w));
    *(ushort4v*)(outl + (size_t)(c0 + c) * R + r0 + r4) = lb;
  }
}

// f32 [B][L][E] -> f32 [B][E][L]
__global__ __launch_bounds__(256) void tpose_f32(
    const float* __restrict__ in, float* __restrict__ out)
{
  __shared__ float t[32][33];
  int b = blockIdx.z;
  const float* ib = in + (size_t)b * L_ * E_;
  float* ob = out + (size_t)b * E_ * L_;
  int c0 = blockIdx.x * 32, r0 = blockIdx.y * 32;   // c over E, r over L
  int tid = threadIdx.x;
  int r = tid >> 3, c4 = (tid & 7) * 4;
  float4 v = *(const float4*)(ib + (size_t)(r0 + r) * E_ + c0 + c4);
  t[r][c4] = v.x; t[r][c4+1] = v.y; t[r][c4+2] = v.z; t[r][c4+3] = v.w;
  __syncthreads();
  int c = tid >> 3, r4 = (tid & 7) * 4;
  float4 o;
  o.x = t[r4][c]; o.y = t[r4+1][c]; o.z = t[r4+2][c]; o.w = t[r4+3][c];
  *(float4*)(ob + (size_t)(c0 + c) * L_ + r0 + r4) = o;
}

// ---------------------------------------------------------------------------
// MFMA GEMM.  MODE 0: plain bf16 (hi only, 1 MFMA pass).
//             MODE 1: split 2-plane bf16 operands (3-pass).
//             MODE 2: f32 operands, split to hi/lo in staging (3-pass).
// C(MxN) = A(MxK) @ Bt(NxK)^T ; 128x128 tile, BK=32, 4 waves, 4x4 frags.
// LDS [kw][plane][slot][8], slot = m ^ (kw<<1)  (round-2-validated geometry).
// ---------------------------------------------------------------------------
enum { EPI_PLAIN = 0, EPI_BIAS = 1, EPI_SILU = 2, EPI_SIG = 3,
       EPI_BIAS_RES = 4, EPI_VDYN = 5, EPI_PV = 6, EPI_TRIL = 7, EPI_RES = 8 };

struct GemmP {
  const ushort_t *A, *Al, *Bt, *Btl;  // MODE 0/1
  const float *Af, *Btf;              // MODE 2
  float* Cf; ushort_t *Cb, *Cbl;
  int N, K, ldA, ldB;
  long long sA, sB, sCf, sCb, sRes, sAux;
  const float *bias, *res, *aux;
  int epi, causal;   // causal: 0 none, 1 tril+skip, 2 kend=row0+128
};

template <int MODE>
__global__ __launch_bounds__(256) void gemm_k(GemmP p)
{
  __shared__ __align__(16) short As[4][2][128][8];
  __shared__ __align__(16) short Bs[4][2][128][8];

  int z = blockIdx.z;
  int row0 = blockIdx.y * 128, col0 = blockIdx.x * 128;
  int tid = threadIdx.x;

  if (p.causal == 1 && col0 > row0) {     // fully above diagonal: zero-fill
    float* Cf = p.Cf ? p.Cf + (size_t)z * p.sCf : nullptr;
    float4 zf = make_float4(0.f, 0.f, 0.f, 0.f);
#pragma unroll
    for (int i = 0; i < 16; ++i) {
      int e4 = tid + 256 * i;
      int r = e4 >> 5, c4 = (e4 & 31) * 4;
      if (Cf) *(float4*)(Cf + (size_t)(row0 + r) * p.N + col0 + c4) = zf;
    }
    return;
  }

  int lane = tid & 63, wave = tid >> 6;
  int wm = wave >> 1, wn = wave & 1;
  int lr = lane & 15, kq = lane >> 4;
  int lrx = lr ^ (kq << 1);

  int kend = p.K;
  if (p.causal == 2) { int ke = row0 + 128; kend = ke < p.K ? ke : p.K; }

  int kw = tid & 3, m0 = tid >> 2, m1 = m0 + 64;
  int sl0 = m0 ^ (kw << 1), sl1 = m1 ^ (kw << 1);

  size_t aoff0 = (size_t)(row0 + m0) * p.ldA + kw * 8;
  size_t aoff1 = (size_t)(row0 + m1) * p.ldA + kw * 8;
  size_t boff0 = (size_t)(col0 + m0) * p.ldB + kw * 8;
  size_t boff1 = (size_t)(col0 + m1) * p.ldB + kw * 8;

  const ushort_t *Ah = nullptr, *Bh = nullptr, *Alo = nullptr, *Blo = nullptr;
  const float *Af = nullptr, *Bf = nullptr;
  if constexpr (MODE == 2) {
    Af = p.Af  + (size_t)z * p.sA;
    Bf = p.Btf + (size_t)z * p.sB;
  } else {
    Ah = p.A  + (size_t)z * p.sA;
    Bh = p.Bt + (size_t)z * p.sB;
    if constexpr (MODE == 1) {
      Alo = p.Al  + (size_t)z * p.sA;
      Blo = p.Btl + (size_t)z * p.sB;
    }
  }

  f32x4 acc[4][4] = {};

  short8 a0h, a1h, b0h, b1h, a0l, a1l, b0l, b1l;
  float fa0[8], fa1[8], fb0[8], fb1[8];

  // initial loads (k0 = 0)
  if constexpr (MODE == 2) {
    *(float4*)&fa0[0] = *(const float4*)(Af + aoff0);
    *(float4*)&fa0[4] = *(const float4*)(Af + aoff0 + 4);
    *(float4*)&fa1[0] = *(const float4*)(Af + aoff1);
    *(float4*)&fa1[4] = *(const float4*)(Af + aoff1 + 4);
    *(float4*)&fb0[0] = *(const float4*)(Bf + boff0);
    *(float4*)&fb0[4] = *(const float4*)(Bf + boff0 + 4);
    *(float4*)&fb1[0] = *(const float4*)(Bf + boff1);
    *(float4*)&fb1[4] = *(const float4*)(Bf + boff1 + 4);
  } else {
    a0h = *(const short8*)(Ah + aoff0);
    a1h = *(const short8*)(Ah + aoff1);
    b0h = *(const short8*)(Bh + boff0);
    b1h = *(const short8*)(Bh + boff1);
    if constexpr (MODE == 1) {
      a0l = *(const short8*)(Alo + aoff0);
      a1l = *(const short8*)(Alo + aoff1);
      b0l = *(const short8*)(Blo + boff0);
      b1l = *(const short8*)(Blo + boff1);
    }
  }

  for (int k0 = 0; k0 < kend; k0 += 32) {
    __syncthreads();                    // previous tile's reads complete
    if constexpr (MODE == 2) {
      split8(fa0, a0h, a0l); split8(fa1, a1h, a1l);
      split8(fb0, b0h, b0l); split8(fb1, b1h, b1l);
    }
    *(short8*)&As[kw][0][sl0][0] = a0h;
    *(short8*)&As[kw][0][sl1][0] = a1h;
    *(short8*)&Bs[kw][0][sl0][0] = b0h;
    *(short8*)&Bs[kw][0][sl1][0] = b1h;
    if constexpr (MODE != 0) {
      *(short8*)&As[kw][1][sl0][0] = a0l;
      *(short8*)&As[kw][1][sl1][0] = a1l;
      *(short8*)&Bs[kw][1][sl0][0] = b0l;
      *(short8*)&Bs[kw][1][sl1][0] = b1l;
    }
    __syncthreads();
    if (k0 + 32 < kend) {               // prefetch next tile (overlaps MFMA)
      size_t kk = k0 + 32;
      if constexpr (MODE == 2) {
        *(float4*)&fa0[0] = *(const float4*)(Af + aoff0 + kk);
        *(float4*)&fa0[4] = *(const float4*)(Af + aoff0 + kk + 4);
        *(float4*)&fa1[0] = *(const float4*)(Af + aoff1 + kk);
        *(float4*)&fa1[4] = *(const float4*)(Af + aoff1 + kk + 4);
        *(float4*)&fb0[0] = *(const float4*)(Bf + boff0 + kk);
        *(float4*)&fb0[4] = *(const float4*)(Bf + boff0 + kk + 4);
        *(float4*)&fb1[0] = *(const float4*)(Bf + boff1 + kk);
        *(float4*)&fb1[4] = *(const float4*)(Bf + boff1 + kk + 4);
      } else {
        a0h = *(const short8*)(Ah + aoff0 + kk);
        a1h = *(const short8*)(Ah + aoff1 + kk);
        b0h = *(const short8*)(Bh + boff0 + kk);
        b1h = *(const short8*)(Bh + boff1 + kk);
        if constexpr (MODE == 1) {
          a0l = *(const short8*)(Alo + aoff0 + kk);
          a1l = *(const short8*)(Alo + aoff1 + kk);
          b0l = *(const short8*)(Blo + boff0 + kk);
          b1l = *(const short8*)(Blo + boff1 + kk);
        }
      }
    }
    short8 bh[4], bl[4];
#pragma unroll
    for (int ni = 0; ni < 4; ++ni) {
      bh[ni] = *(const short8*)&Bs[kq][0][wn * 64 + ni * 16 + lrx][0];
      if (MODE != 0) bl[ni] = *(const short8*)&Bs[kq][1][wn * 64 + ni * 16 + lrx][0];
    }
#pragma unroll
    for (int mi = 0; mi < 4; ++mi) {
      short8 ah = *(const short8*)&As[kq][0][wm * 64 + mi * 16 + lrx][0];
      short8 alv;
      if (MODE != 0) alv = *(const short8*)&As[kq][1][wm * 64 + mi * 16 + lrx][0];
#pragma unroll
      for (int ni = 0; ni < 4; ++ni) {
        acc[mi][ni] = __builtin_amdgcn_mfma_f32_16x16x32_bf16(
            ah, bh[ni], acc[mi][ni], 0, 0, 0);
        if (MODE != 0) {
          acc[mi][ni] = __builtin_amdgcn_mfma_f32_16x16x32_bf16(
              alv, bh[ni], acc[mi][ni], 0, 0, 0);
          acc[mi][ni] = __builtin_amdgcn_mfma_f32_16x16x32_bf16(
              ah, bl[ni], acc[mi][ni], 0, 0, 0);
        }
      }
    }
  }

  float* Cf = p.Cf ? p.Cf + (size_t)z * p.sCf : nullptr;
  ushort_t* Cb  = p.Cb  ? p.Cb  + (size_t)z * p.sCb : nullptr;
  ushort_t* Cbl = p.Cbl ? p.Cbl + (size_t)z * p.sCb : nullptr;
  const float* res = p.res ? p.res + (size_t)z * p.sRes : nullptr;
  const float* aux = p.aux ? p.aux + (size_t)z * p.sAux : nullptr;
  const float INV32 = 0.03125f;
  int rbase = kq * 4;   // D row = (lane>>4)*4 + reg

#pragma unroll
  for (int mi = 0; mi < 4; ++mi) {
#pragma unroll
    for (int r = 0; r < 4; ++r) {
      int grow = row0 + wm * 64 + mi * 16 + rbase + r;
      size_t rowoff = (size_t)grow * p.N;
#pragma unroll
      for (int ni = 0; ni < 4; ++ni) {
        int gcol = col0 + wn * 64 + ni * 16 + lr;
        size_t idx = rowoff + gcol;
        float v = acc[mi][ni][r];
        switch (p.epi) {
          case EPI_PLAIN: break;
          case EPI_BIAS: v += p.bias[gcol]; break;
          case EPI_SILU: v += p.bias[gcol]; v = v / (1.f + expf(-v)); break;
          case EPI_SIG:  v = 1.f / (1.f + expf(-(v + p.bias[gcol]))); break;
          case EPI_BIAS_RES: v += p.bias[gcol] + res[idx]; break;
          case EPI_VDYN: v = aux[idx] * (res[idx] - v * INV32); break;
          case EPI_PV:   v = (res[idx] + v * INV32) * INV32; break;
          case EPI_TRIL: v = (gcol <= grow) ? v : 0.f; break;
          case EPI_RES:  v += res[idx]; break;
        }
        if (Cf) Cf[idx] = v;
        if (Cb) {
          ushort_t hi = f2b(v);
          Cb[idx] = hi;
          if (Cbl) Cbl[idx] = f2b(v - b2f(hi));
        }
      }
    }
  }
}

// ---------------------------------------------------------------------------
// host orchestration
// ---------------------------------------------------------------------------
struct GArgs {
  int mode;
  const ushort_t *A, *Al, *Bt, *Btl;
  const float *Af, *Btf;
  float* Cf; ushort_t *Cb, *Cbl;
  int M, N, K, ldA, ldB, nb;
  long long sA, sB, sCf, sCb, sRes, sAux;
  const float *bias, *res, *aux;
  int epi, causal;
};

static void launch_gemm(const GArgs& a, hipStream_t stream)
{
  GemmP p;
  p.A = a.A; p.Al = a.Al; p.Bt = a.Bt; p.Btl = a.Btl;
  p.Af = a.Af; p.Btf = a.Btf;
  p.Cf = a.Cf; p.Cb = a.Cb; p.Cbl = a.Cbl;
  p.N = a.N; p.K = a.K; p.ldA = a.ldA; p.ldB = a.ldB;
  p.sA = a.sA; p.sB = a.sB; p.sCf = a.sCf; p.sCb = a.sCb;
  p.sRes = a.sRes; p.sAux = a.sAux;
  p.bias = a.bias; p.res = a.res; p.aux = a.aux;
  p.epi = a.epi; p.causal = a.causal;
  dim3 grid(a.N / 128, a.M / 128, a.nb), blk(256);
  if (a.mode == 0)      gemm_k<0><<<grid, blk, 0, stream>>>(p);
  else if (a.mode == 1) gemm_k<1><<<grid, blk, 0, stream>>>(p);
  else                  gemm_k<2><<<grid, blk, 0, stream>>>(p);
}

extern "C" void kernel_launch(void* const* d_in, const int* in_sizes, int n_in,
                              void* d_out, int out_size, void* d_ws, size_t ws_size,
                              hipStream_t stream)
{
  const float* x      = (const float*)d_in[0];
  const float* g_norm = (const float*)d_in[1];
  const float* b_norm = (const float*)d_in[2];
  const float* W1     = (const float*)d_in[3];
  const float* b1     = (const float*)d_in[4];
  const float* W2     = (const float*)d_in[5];
  const float* b2     = (const float*)d_in[6];
  const float* g_head = (const float*)d_in[7];
  const float* b_head = (const float*)d_in[8];
  const float* memW   = (const float*)d_in[9];
  const float* g_mem  = (const float*)d_in[10];
  const float* b_mem  = (const float*)d_in[11];
  const float* W_q    = (const float*)d_in[12];
  const float* b_q    = (const float*)d_in[13];
  const float* W_k    = (const float*)d_in[14];
  const float* b_k    = (const float*)d_in[15];
  const float* W_v    = (const float*)d_in[16];
  const float* b_v    = (const float*)d_in[17];
  const float* W_g    = (const float*)d_in[18];
  const float* b_g    = (const float*)d_in[19];
  const float* W_o    = (const float*)d_in[22];
  const float* b_o    = (const float*)d_in[23];
  const float* W_op   = (const float*)d_in[24];
  const float* b_op   = (const float*)d_in[25];
  const float* g_ctx  = (const float*)d_in[26];
  const float* b_ctx  = (const float*)d_in[27];

  float* out = (float*)d_out;
  char* w = (char*)d_ws;
  auto alloc = [&](size_t bytes) { char* p = w; w += (bytes + 255) & ~(size_t)255; return p; };

  const size_t ME  = (size_t)M_ * E_;
  const size_t EE  = (size_t)E_ * E_;
  const size_t E4E = (size_t)E_ * E4_;

  // weights: FFN hi-only; sensitive-chain 2-plane (hi | lo)
  ushort_t* W1t  = (ushort_t*)alloc((size_t)FF_ * E_ * 2);
  ushort_t* W2t  = (ushort_t*)alloc((size_t)E_ * FF_ * 2);
  ushort_t* Wqt  = (ushort_t*)alloc(2 * EE * 2);
  ushort_t* Wkt  = (ushort_t*)alloc(2 * EE * 2);
  ushort_t* Wvt  = (ushort_t*)alloc(2 * EE * 2);
  ushort_t* Wgt  = (ushort_t*)alloc(2 * EE * 2);
  ushort_t* memT = (ushort_t*)alloc(2 * EE * 2);
  ushort_t* Wot  = (ushort_t*)alloc(2 * E4E * 2);
  ushort_t* Wopt = (ushort_t*)alloc(2 * E4E * 2);
  // f32 activations
  float* P0 = (float*)alloc(ME * 4);   // xmlp (live to end)
  float* P1 = (float*)alloc(ME * 4);
  float* P2 = (float*)alloc(ME * 4);
  // 2-plane bf16 activations (hi | lo, plane stride ME)
  ushort_t* Q1 = (ushort_t*)alloc(2 * ME * 2);  // xnormH / ctx2p / vdyn-f32
  ushort_t* Q2 = (ushort_t*)alloc(2 * ME * 2);  // q2p -> mem_out2p
  ushort_t* Q3 = (ushort_t*)alloc(2 * ME * 2);  // k2p
  // shared big region: h1 (M x FF plain) then out_h chunks (2p M x 1024)
  ushort_t* SH = (ushort_t*)alloc((size_t)M_ * FF_ * 2);
  float* Sb = (float*)alloc((size_t)B_ * NC_ * E_ * 4);
  float* Gb = (float*)alloc((size_t)B_ * NC_ * E_ * 4);
  if ((size_t)(w - (char*)d_ws) > ws_size) return;   // ws too small -> stub-like fail

  float* y_out  = out;
  float* sc_out = out + ME;

  // weight conversion + transpose (f32 RxC -> bf16 CxR planes)
  wcvt_t<<<dim3(FF_/32, E_/32),  256, 0, stream>>>(W1,   W1t,  nullptr,    E_,  FF_);
  wcvt_t<<<dim3(E_/32,  FF_/32), 256, 0, stream>>>(W2,   W2t,  nullptr,    FF_, E_);
  wcvt_t<<<dim3(E_/32,  E_/32),  256, 0, stream>>>(W_q,  Wqt,  Wqt + EE,   E_,  E_);
  wcvt_t<<<dim3(E_/32,  E_/32),  256, 0, stream>>>(W_k,  Wkt,  Wkt + EE,   E_,  E_);
  wcvt_t<<<dim3(E_/32,  E_/32),  256, 0, stream>>>(W_v,  Wvt,  Wvt + EE,   E_,  E_);
  wcvt_t<<<dim3(E_/32,  E_/32),  256, 0, stream>>>(W_g,  Wgt,  Wgt + EE,   E_,  E_);
  wcvt_t<<<dim3(E_/32,  E_/32),  256, 0, stream>>>(memW, memT, memT + EE,  E_,  E_);
  wcvt_t<<<dim3(E4_/32, E_/32),  256, 0, stream>>>(W_o,  Wot,  Wot + E4E,  E_,  E4_);
  wcvt_t<<<dim3(E_/32,  E4_/32), 256, 0, stream>>>(W_op, Wopt, Wopt + E4E, E4_, E_);

  GArgs g{};

  // 1. x_norm = LN(x) -> bf16 hi (Q1)
  ln_rows<<<M_, 256, 0, stream>>>(x, g_norm, b_norm, nullptr, nullptr, Q1, nullptr);
  // 2. h1 = silu(x_norm @ W1 + b1) -> SH plain bf16
  g = GArgs(); g.mode = 0; g.A = Q1; g.Bt = W1t; g.Cb = SH;
  g.M = M_; g.N = FF_; g.K = E_; g.ldA = E_; g.ldB = E_; g.nb = 1;
  g.bias = b1; g.epi = EPI_SILU; launch_gemm(g, stream);
  // 3. x_mlp = x + h1 @ W2 + b2 -> P0
  g = GArgs(); g.mode = 0; g.A = SH; g.Bt = W2t; g.Cf = P0;
  g.M = M_; g.N = E_; g.K = FF_; g.ldA = FF_; g.ldB = FF_; g.nb = 1;
  g.bias = b2; g.res = x; g.epi = EPI_BIAS_RES; launch_gemm(g, stream);
  // 4-8. cumsum gating chain
  chunk_partials<<<dim3(NC_, B_), 256, 0, stream>>>(P0, Sb);
  scan_partials<<<B_, 256, 0, stream>>>(Sb);
  align_gate<<<dim3(NC_, H_, B_), 64, 0, stream>>>(P0, Sb, g_head, b_head, P1, Gb);
  scan_partials<<<B_, 256, 0, stream>>>(Gb);
  context_add<<<dim3(NC_, B_), 256, 0, stream>>>(P1, Gb, P0, P2);
  // 9. ctx = LN(t) -> Q1 2p
  ln_rows<<<M_, 256, 0, stream>>>(P2, g_mem, b_mem, nullptr, nullptr, Q1, Q1 + ME);
  // 10. q -> Q2 2p
  g = GArgs(); g.mode = 1; g.A = Q1; g.Al = Q1 + ME; g.Bt = Wqt; g.Btl = Wqt + EE;
  g.Cb = Q2; g.Cbl = Q2 + ME; g.M = M_; g.N = E_; g.K = E_; g.ldA = E_; g.ldB = E_;
  g.nb = 1; g.bias = b_q; g.epi = EPI_BIAS; launch_gemm(g, stream);
  // 11. kraw -> P1 f32 ; knorm -> Q3 2p
  g.Bt = Wkt; g.Btl = Wkt + EE; g.Cb = nullptr; g.Cbl = nullptr; g.Cf = P1;
  g.bias = b_k; launch_gemm(g, stream);
  knorm_rows<<<M_, 256, 0, stream>>>(P1, Q3, Q3 + ME);
  // 12. v -> P1 f32 (kraw dead)
  g.Bt = Wvt; g.Btl = Wvt + EE; g.Cf = P1; g.bias = b_v; launch_gemm(g, stream);
  // 13. gate -> P2 f32 (t dead)
  g.Bt = Wgt; g.Btl = Wgt + EE; g.Cf = P2; g.bias = b_g; g.epi = EPI_SIG;
  launch_gemm(g, stream);
  // 14. v_dyn = gate * (v - (k @ mem)/32) -> (float*)Q1 (ctx dead)
  g = GArgs(); g.mode = 1; g.A = Q3; g.Al = Q3 + ME; g.Bt = memT; g.Btl = memT + EE;
  g.Cf = (float*)Q1; g.M = M_; g.N = E_; g.K = E_; g.ldA = E_; g.ldB = E_; g.nb = 1;
  g.res = P1; g.aux = P2; g.epi = EPI_VDYN; launch_gemm(g, stream);
  // 15. vdynT f32 [B][E][L] -> P1 (v dead)
  tpose_f32<<<dim3(E_/32, L_/32, B_), 256, 0, stream>>>((float*)Q1, P1);
  // 16. scores = tril(q @ k^T) -> d_out f32 only
  g = GArgs(); g.mode = 1; g.A = Q2; g.Al = Q2 + ME; g.Bt = Q3; g.Btl = Q3 + ME;
  g.Cf = sc_out; g.M = L_; g.N = L_; g.K = E_; g.ldA = E_; g.ldB = E_; g.nb = B_;
  g.sA = (long long)L_ * E_; g.sB = (long long)L_ * E_; g.sCf = (long long)L_ * L_;
  g.epi = EPI_TRIL; g.causal = 1; launch_gemm(g, stream);
  // 17. mem_out_prev = q @ mem -> P2 (gate dead)
  g = GArgs(); g.mode = 1; g.A = Q2; g.Al = Q2 + ME; g.Bt = memT; g.Btl = memT + EE;
  g.Cf = P2; g.M = M_; g.N = E_; g.K = E_; g.ldA = E_; g.ldB = E_; g.nb = 1;
  g.epi = EPI_PLAIN; launch_gemm(g, stream);
  // 18. mem_out = (prev + scores @ v_dyn /32)/32 -> Q2 2p (q dead); f32 operands
  g = GArgs(); g.mode = 2; g.Af = sc_out; g.Btf = P1;
  g.Cb = Q2; g.Cbl = Q2 + ME; g.M = L_; g.N = E_; g.K = L_; g.ldA = L_; g.ldB = L_;
  g.nb = B_; g.sA = (long long)L_ * L_; g.sB = (long long)E_ * L_;
  g.sCb = (long long)L_ * E_; g.sRes = (long long)L_ * E_;
  g.res = P2; g.epi = EPI_PV; g.causal = 2; launch_gemm(g, stream);
  // 19-20. output MLP, E4 chunked by 1024: out -> P1 (acc), final +bias -> P2
  const size_t SHLO = (size_t)M_ * 1024;
  for (int c = 0; c < 4; ++c) {
    // out_h_c = silu(mem_out @ W_o[:, c*1024:(c+1)*1024] + b_o[c]) -> SH 2p
    g = GArgs(); g.mode = 1; g.A = Q2; g.Al = Q2 + ME;
    g.Bt = Wot + (size_t)c * 1024 * E_; g.Btl = Wot + E4E + (size_t)c * 1024 * E_;
    g.Cb = SH; g.Cbl = SH + SHLO;
    g.M = M_; g.N = 1024; g.K = E_; g.ldA = E_; g.ldB = E_; g.nb = 1;
    g.bias = b_o + c * 1024; g.epi = EPI_SILU; launch_gemm(g, stream);
    // out += out_h_c @ W_op[c*1024:(c+1)*1024, :]
    g = GArgs(); g.mode = 1; g.A = SH; g.Al = SH + SHLO;
    g.Bt = Wopt + (size_t)c * 1024; g.Btl = Wopt + E4E + (size_t)c * 1024;
    g.M = M_; g.N = E_; g.K = 1024; g.ldA = 1024; g.ldB = E4_; g.nb = 1;
    if (c == 0) { g.Cf = P1; g.epi = EPI_PLAIN; }
    else if (c < 3) { g.Cf = P1; g.res = P1; g.epi = EPI_RES; }
    else { g.Cf = P2; g.res = P1; g.bias = b_op; g.epi = EPI_BIAS_RES; }
    launch_gemm(g, stream);
  }
  // 21. y = x_mlp + LN(out)
  ln_rows<<<M_, 256, 0, stream>>>(P2, g_ctx, b_ctx, P0, y_out, nullptr, nullptr);
}